// Round 1
// baseline (1199.464 us; speedup 1.0000x reference)
//
#include <hip/hip_runtime.h>
#include <hip/hip_bf16.h>

// Criss-Cross Attention, MI355X. Round 1: full bf16-MFMA pipeline.
// B=8, C=512, C8=64, S=128. All MFMA = 16x16x32 bf16 (verified layouts only):
//   a/b frag: M[row = lane&15][k = (lane>>4)*8 + j], D = A * B^T
//   D frag:   D[row = (lane>>4)*4 + reg][col = lane&15]

#define S 128
#define SS 16384
#define C 512
#define C8 64
#define NEG_BIG -1000000000.0f

using short8 = __attribute__((ext_vector_type(8))) short;
using f32x4  = __attribute__((ext_vector_type(4))) float;

__device__ __forceinline__ unsigned short f2b(float f){
  union { float f; unsigned u; } v; v.f = f;
  unsigned r = (v.u + 0x7fffu + ((v.u >> 16) & 1u)) >> 16;
  return (unsigned short)r;
}
__device__ __forceinline__ float b2f(unsigned short h){
  union { unsigned u; float f; } v; v.u = ((unsigned)h) << 16;
  return v.f;
}

// ---------------- K0a: pack Wq|Wk|Wv -> wall[640][512] bf16 ----------------
__global__ __launch_bounds__(256) void k_pack_w(
    const float* __restrict__ Wq, const float* __restrict__ Wk,
    const float* __restrict__ Wv, unsigned short* __restrict__ wall){
  int i = blockIdx.x * 256 + threadIdx.x;
  if (i >= 640 * C) return;
  int co = i >> 9, ci = i & (C - 1);
  float v;
  if (co < 64)        v = Wq[co * C + ci];
  else if (co < 128)  v = Wk[(co - 64) * C + ci];
  else                v = Wv[(co - 128) * C + ci];
  wall[i] = f2b(v);
}

// ---------------- K0b: x (f32, [b][ci][w][h]) -> xp (bf16, [b][w][h][ci]) ----
__global__ __launch_bounds__(256) void k_xp(
    const float* __restrict__ x, unsigned short* __restrict__ xp){
  __shared__ unsigned short T[128 * 130] __attribute__((aligned(16)));
  int blk = blockIdx.x;                 // ((b*128 + w)*4 + ct)
  int ct = blk & 3; int bw = blk >> 2;
  int w = bw & 127; int b = bw >> 7;
  int tid = threadIdx.x;
  int ci0 = ct * 128;
  const float* xb = x + ((size_t)(b * C + ci0) * S + w) * S;  // + cc*SS + h
  #pragma unroll
  for (int p = 0; p < 16; ++p){
    int idx = p * 256 + tid;            // 0..4095
    int cc = idx >> 5;
    int h4 = (idx & 31) * 4;
    float4 v = *(const float4*)(xb + (size_t)cc * SS + h4);
    unsigned* d = (unsigned*)&T[cc * 130 + h4];
    d[0] = (unsigned)f2b(v.x) | ((unsigned)f2b(v.y) << 16);
    d[1] = (unsigned)f2b(v.z) | ((unsigned)f2b(v.w) << 16);
  }
  __syncthreads();
  unsigned short* xpb = xp + (size_t)(b * S + w) * S * C + ci0;
  #pragma unroll
  for (int p = 0; p < 8; ++p){
    int idx = p * 256 + tid;            // 0..2047
    int h  = idx >> 4;
    int ch = (idx & 15) * 8;            // cc chunk
    unsigned short tmp[8] __attribute__((aligned(16)));
    #pragma unroll
    for (int j = 0; j < 8; ++j) tmp[j] = T[(ch + j) * 130 + h];
    *(uint4*)(xpb + (size_t)h * C + ch) = *(uint4*)tmp;
  }
}

// ---------------- K1: qkv projection GEMM ----------------
// block = ((b*128+w)*5 + cot). cot0 -> q(64)+k(64), cot1..4 -> v co-tiles.
__global__ __launch_bounds__(256) void k_qkv(
    const unsigned short* __restrict__ xp, const unsigned short* __restrict__ wall,
    const float* __restrict__ bq, const float* __restrict__ bk,
    const float* __restrict__ bv,
    unsigned short* __restrict__ qp, unsigned short* __restrict__ kp,
    unsigned short* __restrict__ vb){
  __shared__ unsigned short Xl[128 * 72] __attribute__((aligned(16)));
  __shared__ unsigned short Wl[128 * 72] __attribute__((aligned(16)));
  int blk = blockIdx.x;
  int cot = blk % 5; int bw = blk / 5;
  int w = bw & 127, b = bw >> 7;
  int tid = threadIdx.x, lane = tid & 63, wid = tid >> 6;
  int qd = lane >> 4, ln = lane & 15;
  int coq = (wid & 1) * 4;              // co sub-tile base
  int pq  = (wid >> 1) * 4;             // pixel sub-tile base
  const unsigned short* xpb = xp + (size_t)(b * S + w) * S * C;   // [p][ci]
  const unsigned short* wb  = wall + (size_t)cot * 128 * C;       // [co_l][ci]
  f32x4 acc[4][4];
  #pragma unroll
  for (int i = 0; i < 4; ++i)
    #pragma unroll
    for (int j = 0; j < 4; ++j) acc[i][j] = (f32x4){0.f, 0.f, 0.f, 0.f};

  for (int kw = 0; kw < 8; ++kw){
    __syncthreads();
    #pragma unroll
    for (int p2 = 0; p2 < 4; ++p2){
      int idx = p2 * 256 + tid;         // 0..1023
      int row = idx >> 3, ch = (idx & 7) * 8;
      *(uint4*)&Xl[row * 72 + ch] = *(const uint4*)(xpb + (size_t)row * C + kw * 64 + ch);
      *(uint4*)&Wl[row * 72 + ch] = *(const uint4*)(wb  + (size_t)row * C + kw * 64 + ch);
    }
    __syncthreads();
    #pragma unroll
    for (int ks = 0; ks < 2; ++ks){
      int ko = ks * 32 + qd * 8;        // element offset in 64-window
      short8 af[4], bfr[4];
      #pragma unroll
      for (int i = 0; i < 4; ++i)
        af[i] = *(const short8*)&Wl[((coq + i) * 16 + ln) * 72 + ko];
      #pragma unroll
      for (int j = 0; j < 4; ++j)
        bfr[j] = *(const short8*)&Xl[((pq + j) * 16 + ln) * 72 + ko];
      #pragma unroll
      for (int i = 0; i < 4; ++i)
        #pragma unroll
        for (int j = 0; j < 4; ++j)
          acc[i][j] = __builtin_amdgcn_mfma_f32_16x16x32_bf16(af[i], bfr[j], acc[i][j], 0, 0, 0);
    }
  }
  // epilogue
  #pragma unroll
  for (int i = 0; i < 4; ++i){
    int col0 = (coq + i) * 16 + qd * 4;           // co_local base
    #pragma unroll
    for (int j = 0; j < 4; ++j){
      int h = (pq + j) * 16 + ln;
      #pragma unroll
      for (int r = 0; r < 4; ++r){
        int col = col0 + r;
        float val = acc[i][j][r];
        if (cot == 0){
          if (col < 64)
            qp[((size_t)(b * S + w) * S + h) * C8 + col] = f2b(val + bq[col]);
          else
            kp[((size_t)(b * S + w) * S + h) * C8 + (col - 64)] = f2b(val + bk[col - 64]);
        } else {
          int vco = (cot - 1) * 128 + col;
          vb[((size_t)(b * C + vco) * S + w) * S + h] = f2b(val + bv[vco]);
        }
      }
    }
  }
}

// ---------------- K2: vb [b][c][w][h] -> vt [b][c][h][w] ----------------
__global__ __launch_bounds__(256) void k_tv(
    const unsigned short* __restrict__ vb, unsigned short* __restrict__ vt){
  __shared__ unsigned short T[128 * 130] __attribute__((aligned(16)));
  int bc = blockIdx.x;                  // b*C + c
  const unsigned short* src = vb + (size_t)bc * SS;
  unsigned short* dst = vt + (size_t)bc * SS;
  int tid = threadIdx.x;
  #pragma unroll
  for (int p = 0; p < 8; ++p){
    int idx = p * 256 + tid;            // 0..2047
    int wv = idx >> 4, ch = (idx & 15) * 8;
    uint4 v = *(const uint4*)(src + wv * S + ch);
    unsigned* d = (unsigned*)&T[wv * 130 + ch];
    d[0] = v.x; d[1] = v.y; d[2] = v.z; d[3] = v.w;
  }
  __syncthreads();
  #pragma unroll
  for (int p = 0; p < 8; ++p){
    int idx = p * 256 + tid;
    int h = idx >> 4, ch = (idx & 15) * 8;
    unsigned short tmp[8] __attribute__((aligned(16)));
    #pragma unroll
    for (int j = 0; j < 8; ++j) tmp[j] = T[(ch + j) * 130 + h];
    *(uint4*)(dst + h * S + ch) = *(uint4*)tmp;
  }
}

// ---------------- K3: column scores e_col[b][w][h][u] (masked diag), bf16 ---
__global__ __launch_bounds__(256) void k_ecol(
    const unsigned short* __restrict__ qp, const unsigned short* __restrict__ kp,
    unsigned short* __restrict__ eca){
  __shared__ unsigned short Aq[128 * 72] __attribute__((aligned(16)));
  __shared__ unsigned short Bk[128 * 72] __attribute__((aligned(16)));
  int blk = blockIdx.x; int h = blk & 127, b = blk >> 7;
  int tid = threadIdx.x, lane = tid & 63, wid = tid >> 6;
  int qd = lane >> 4, ln = lane & 15;
  #pragma unroll
  for (int p = 0; p < 4; ++p){
    int idx = p * 256 + tid;
    int row = idx >> 3, ch = (idx & 7) * 8;
    *(uint4*)&Aq[row * 72 + ch] = *(const uint4*)(qp + ((size_t)(b * S + row) * S + h) * C8 + ch);
    *(uint4*)&Bk[row * 72 + ch] = *(const uint4*)(kp + ((size_t)(b * S + row) * S + h) * C8 + ch);
  }
  __syncthreads();
  f32x4 acc[4][4];
  #pragma unroll
  for (int i = 0; i < 4; ++i)
    #pragma unroll
    for (int j = 0; j < 4; ++j) acc[i][j] = (f32x4){0.f, 0.f, 0.f, 0.f};
  #pragma unroll
  for (int ks = 0; ks < 2; ++ks){
    int ko = ks * 32 + qd * 8;
    short8 af[4], bfr[4];
    #pragma unroll
    for (int i = 0; i < 4; ++i)
      af[i] = *(const short8*)&Aq[(((wid & 1) * 4 + i) * 16 + ln) * 72 + ko];
    #pragma unroll
    for (int j = 0; j < 4; ++j)
      bfr[j] = *(const short8*)&Bk[(((wid >> 1) * 4 + j) * 16 + ln) * 72 + ko];
    #pragma unroll
    for (int i = 0; i < 4; ++i)
      #pragma unroll
      for (int j = 0; j < 4; ++j)
        acc[i][j] = __builtin_amdgcn_mfma_f32_16x16x32_bf16(af[i], bfr[j], acc[i][j], 0, 0, 0);
  }
  #pragma unroll
  for (int i = 0; i < 4; ++i){
    int w0 = ((wid & 1) * 4 + i) * 16 + qd * 4;
    #pragma unroll
    for (int j = 0; j < 4; ++j){
      int ug = ((wid >> 1) * 4 + j) * 16 + ln;
      #pragma unroll
      for (int r = 0; r < 4; ++r){
        int wg = w0 + r;
        float val = acc[i][j][r];
        if (wg == ug) val = NEG_BIG;
        eca[((size_t)(b * S + wg) * S + h) * S + ug] = f2b(val);
      }
    }
  }
}

// ------- K4: row scores + joint softmax; ac overwrites eca in place; ar out --
__global__ __launch_bounds__(256) void k_erow_softmax(
    const unsigned short* __restrict__ qp, const unsigned short* __restrict__ kp,
    unsigned short* __restrict__ eca, unsigned short* __restrict__ ar){
  __shared__ char sm[36864] __attribute__((aligned(16)));
  unsigned short* Aq = (unsigned short*)sm;              // [128][72]
  unsigned short* Bk = (unsigned short*)(sm + 18432);    // [128][72]
  unsigned short* El = (unsigned short*)sm;              // alias: [128][132] bf16
  float* redm = (float*)(sm + 33792);                    // [256]
  float* reds = (float*)(sm + 34816);                    // [256]
  int blk = blockIdx.x; int w = blk & 127, b = blk >> 7;
  int tid = threadIdx.x, lane = tid & 63, wid = tid >> 6;
  int qd = lane >> 4, ln = lane & 15;
  size_t tb = (size_t)(b * S + w) * SS;                  // tile base (elems)
  {
    const unsigned short* qsrc = qp + (size_t)(b * S + w) * S * C8;
    const unsigned short* ksrc = kp + (size_t)(b * S + w) * S * C8;
    #pragma unroll
    for (int p = 0; p < 4; ++p){
      int idx = p * 256 + tid;
      int row = idx >> 3, ch = (idx & 7) * 8;
      *(uint4*)&Aq[row * 72 + ch] = *(const uint4*)(qsrc + row * C8 + ch);
      *(uint4*)&Bk[row * 72 + ch] = *(const uint4*)(ksrc + row * C8 + ch);
    }
  }
  __syncthreads();
  f32x4 acc[4][4];
  #pragma unroll
  for (int i = 0; i < 4; ++i)
    #pragma unroll
    for (int j = 0; j < 4; ++j) acc[i][j] = (f32x4){0.f, 0.f, 0.f, 0.f};
  #pragma unroll
  for (int ks = 0; ks < 2; ++ks){
    int ko = ks * 32 + qd * 8;
    short8 af[4], bfr[4];
    #pragma unroll
    for (int i = 0; i < 4; ++i)
      af[i] = *(const short8*)&Aq[(((wid & 1) * 4 + i) * 16 + ln) * 72 + ko];
    #pragma unroll
    for (int j = 0; j < 4; ++j)
      bfr[j] = *(const short8*)&Bk[(((wid >> 1) * 4 + j) * 16 + ln) * 72 + ko];
    #pragma unroll
    for (int i = 0; i < 4; ++i)
      #pragma unroll
      for (int j = 0; j < 4; ++j)
        acc[i][j] = __builtin_amdgcn_mfma_f32_16x16x32_bf16(af[i], bfr[j], acc[i][j], 0, 0, 0);
  }
  __syncthreads();     // done with Aq/Bk; El may now alias them
  #pragma unroll
  for (int i = 0; i < 4; ++i){
    int h0 = ((wid & 1) * 4 + i) * 16 + qd * 4;
    #pragma unroll
    for (int j = 0; j < 4; ++j){
      int ul = ((wid >> 1) * 4 + j) * 16 + ln;
      #pragma unroll
      for (int r = 0; r < 4; ++r)
        El[(h0 + r) * 132 + ul] = f2b(acc[i][j][r]);
    }
  }
  __syncthreads();
  // softmax over 256 = [col(128 from eca) | row(128 from El)] per h
  int h = tid >> 1, half = tid & 1;
  const unsigned short* colrow = eca + tb + (size_t)h * S;
  float mx = -3.0e38f;
  if (half == 0){
    for (int u = 0; u < 128; ++u) mx = fmaxf(mx, b2f(colrow[u]));
  } else {
    for (int u = 0; u < 128; ++u) mx = fmaxf(mx, b2f(El[h * 132 + u]));
  }
  redm[tid] = mx;
  __syncthreads();
  float m = fmaxf(redm[h * 2], redm[h * 2 + 1]);
  float s = 0.f;
  if (half == 0){
    for (int u = 0; u < 128; ++u) s += __expf(b2f(colrow[u]) - m);
  } else {
    for (int u = 0; u < 128; ++u) s += __expf(b2f(El[h * 132 + u]) - m);
  }
  reds[tid] = s;
  __syncthreads();
  float inv = 1.0f / (reds[h * 2] + reds[h * 2 + 1]);
  if (half == 0){
    unsigned short* dst = eca + tb + (size_t)h * S;       // ac, in place
    for (int u = 0; u < 128; ++u) dst[u] = f2b(__expf(b2f(colrow[u]) - m) * inv);
  } else {
    unsigned short* dst = ar + tb + (size_t)h * S;
    for (int u = 0; u < 128; ++u) dst[u] = f2b(__expf(b2f(El[h * 132 + u]) - m) * inv);
  }
}

// ------- K5: out_row: out = gamma * (A_row @ v_row) + x  (writes all of out) --
__global__ __launch_bounds__(256) void k_outrow(
    const unsigned short* __restrict__ vb, const unsigned short* __restrict__ ar,
    const float* __restrict__ x, const float* __restrict__ gamma,
    float* __restrict__ out){
  __shared__ unsigned short Av[128 * 72] __attribute__((aligned(16)));
  __shared__ unsigned short Ba[128 * 72] __attribute__((aligned(16)));
  int blk = blockIdx.x;                 // ((b*128+w)*4 + ct)
  int ct = blk & 3; int bw = blk >> 2;
  int w = bw & 127, b = bw >> 7;
  int tid = threadIdx.x, lane = tid & 63, wid = tid >> 6;
  int qd = lane >> 4, ln = lane & 15;
  size_t tb = (size_t)(b * S + w) * SS;
  f32x4 acc[4][4];
  #pragma unroll
  for (int i = 0; i < 4; ++i)
    #pragma unroll
    for (int j = 0; j < 4; ++j) acc[i][j] = (f32x4){0.f, 0.f, 0.f, 0.f};
  for (int kw = 0; kw < 2; ++kw){
    __syncthreads();
    #pragma unroll
    for (int p = 0; p < 4; ++p){
      int idx = p * 256 + tid;
      int row = idx >> 3, ch = (idx & 7) * 8;
      *(uint4*)&Av[row * 72 + ch] =
        *(const uint4*)(vb + ((size_t)(b * C + ct * 128 + row) * S + w) * S + kw * 64 + ch);
      *(uint4*)&Ba[row * 72 + ch] =
        *(const uint4*)(ar + tb + (size_t)row * S + kw * 64 + ch);
    }
    __syncthreads();
    #pragma unroll
    for (int ks = 0; ks < 2; ++ks){
      int ko = ks * 32 + qd * 8;
      short8 af[4], bfr[4];
      #pragma unroll
      for (int i = 0; i < 4; ++i)
        af[i] = *(const short8*)&Av[(((wid & 1) * 4 + i) * 16 + ln) * 72 + ko];
      #pragma unroll
      for (int j = 0; j < 4; ++j)
        bfr[j] = *(const short8*)&Ba[(((wid >> 1) * 4 + j) * 16 + ln) * 72 + ko];
      #pragma unroll
      for (int i = 0; i < 4; ++i)
        #pragma unroll
        for (int j = 0; j < 4; ++j)
          acc[i][j] = __builtin_amdgcn_mfma_f32_16x16x32_bf16(af[i], bfr[j], acc[i][j], 0, 0, 0);
    }
  }
  float g = gamma[0];
  #pragma unroll
  for (int i = 0; i < 4; ++i){
    int c0 = ((wid & 1) * 4 + i) * 16 + qd * 4;
    #pragma unroll
    for (int j = 0; j < 4; ++j){
      int hl = ((wid >> 1) * 4 + j) * 16 + ln;
      #pragma unroll
      for (int r = 0; r < 4; ++r){
        int cg = ct * 128 + c0 + r;
        size_t o = ((size_t)(b * C + cg) * S + w) * S + hl;
        out[o] = g * acc[i][j][r] + x[o];
      }
    }
  }
}

// ------- K6: out_col -> oct[b][h][c][w] bf16 ----------------
__global__ __launch_bounds__(256) void k_outcol(
    const unsigned short* __restrict__ vt, const unsigned short* __restrict__ eca,
    unsigned short* __restrict__ oct){
  __shared__ unsigned short Av[128 * 72] __attribute__((aligned(16)));
  __shared__ unsigned short Ba[128 * 72] __attribute__((aligned(16)));
  int blk = blockIdx.x;                 // ((b*128+h)*4 + ct)
  int ct = blk & 3; int bh = blk >> 2;
  int h = bh & 127, b = bh >> 7;
  int tid = threadIdx.x, lane = tid & 63, wid = tid >> 6;
  int qd = lane >> 4, ln = lane & 15;
  f32x4 acc[4][4];
  #pragma unroll
  for (int i = 0; i < 4; ++i)
    #pragma unroll
    for (int j = 0; j < 4; ++j) acc[i][j] = (f32x4){0.f, 0.f, 0.f, 0.f};
  for (int kw = 0; kw < 2; ++kw){
    __syncthreads();
    #pragma unroll
    for (int p = 0; p < 4; ++p){
      int idx = p * 256 + tid;
      int row = idx >> 3, ch = (idx & 7) * 8;
      *(uint4*)&Av[row * 72 + ch] =
        *(const uint4*)(vt + ((size_t)(b * C + ct * 128 + row) * S + h) * S + kw * 64 + ch);
      *(uint4*)&Ba[row * 72 + ch] =
        *(const uint4*)(eca + ((size_t)(b * S + row) * S + h) * S + kw * 64 + ch);
    }
    __syncthreads();
    #pragma unroll
    for (int ks = 0; ks < 2; ++ks){
      int ko = ks * 32 + qd * 8;
      short8 af[4], bfr[4];
      #pragma unroll
      for (int i = 0; i < 4; ++i)
        af[i] = *(const short8*)&Av[(((wid & 1) * 4 + i) * 16 + ln) * 72 + ko];
      #pragma unroll
      for (int j = 0; j < 4; ++j)
        bfr[j] = *(const short8*)&Ba[(((wid >> 1) * 4 + j) * 16 + ln) * 72 + ko];
      #pragma unroll
      for (int i = 0; i < 4; ++i)
        #pragma unroll
        for (int j = 0; j < 4; ++j)
          acc[i][j] = __builtin_amdgcn_mfma_f32_16x16x32_bf16(af[i], bfr[j], acc[i][j], 0, 0, 0);
    }
  }
  #pragma unroll
  for (int i = 0; i < 4; ++i){
    int c0 = ((wid & 1) * 4 + i) * 16 + qd * 4;
    #pragma unroll
    for (int j = 0; j < 4; ++j){
      int wl = ((wid >> 1) * 4 + j) * 16 + ln;
      #pragma unroll
      for (int r = 0; r < 4; ++r){
        int cg = ct * 128 + c0 + r;
        oct[((size_t)(b * S + h) * C + cg) * S + wl] = f2b(acc[i][j][r]);
      }
    }
  }
}

// ------- K7: out += gamma * transpose(oct) ----------------
__global__ __launch_bounds__(256) void k_final(
    const unsigned short* __restrict__ oct, const float* __restrict__ gamma,
    float* __restrict__ out){
  __shared__ unsigned short T[128 * 130] __attribute__((aligned(16)));
  int blk = blockIdx.x;                 // b*C + c
  int c = blk & 511, b = blk >> 9;
  int tid = threadIdx.x;
  float g = gamma[0];
  #pragma unroll
  for (int p = 0; p < 8; ++p){
    int idx = p * 256 + tid;
    int hh = idx >> 4, ch = (idx & 15) * 8;
    uint4 v = *(const uint4*)(oct + ((size_t)(b * S + hh) * C + c) * S + ch);
    unsigned* d = (unsigned*)&T[hh * 130 + ch];
    d[0] = v.x; d[1] = v.y; d[2] = v.z; d[3] = v.w;
  }
  __syncthreads();
  #pragma unroll
  for (int p = 0; p < 8; ++p){
    int idx = p * 256 + tid;
    int wv = idx >> 4, hch = (idx & 15) * 8;
    size_t o = ((size_t)(b * C + c) * S + wv) * S + hch;
    float4 o0 = *(float4*)(out + o);
    float4 o1 = *(float4*)(out + o + 4);
    o0.x += g * b2f(T[(hch + 0) * 130 + wv]);
    o0.y += g * b2f(T[(hch + 1) * 130 + wv]);
    o0.z += g * b2f(T[(hch + 2) * 130 + wv]);
    o0.w += g * b2f(T[(hch + 3) * 130 + wv]);
    o1.x += g * b2f(T[(hch + 4) * 130 + wv]);
    o1.y += g * b2f(T[(hch + 5) * 130 + wv]);
    o1.z += g * b2f(T[(hch + 6) * 130 + wv]);
    o1.w += g * b2f(T[(hch + 7) * 130 + wv]);
    *(float4*)(out + o) = o0;
    *(float4*)(out + o + 4) = o1;
  }
}

extern "C" void kernel_launch(void* const* d_in, const int* in_sizes, int n_in,
                              void* d_out, int out_size, void* d_ws, size_t ws_size,
                              hipStream_t stream){
  const float* x     = (const float*)d_in[0];
  const float* Wq    = (const float*)d_in[1];
  const float* bq    = (const float*)d_in[2];
  const float* Wk    = (const float*)d_in[3];
  const float* bk    = (const float*)d_in[4];
  const float* Wv    = (const float*)d_in[5];
  const float* bv    = (const float*)d_in[6];
  const float* gamma = (const float*)d_in[7];
  float* out = (float*)d_out;
  char* ws = (char*)d_ws;

  const size_t OFF_WALL = 0;
  const size_t OFF_XP   = 1ull << 20;                    // 134,217,728
  const size_t OFF_QP   = OFF_XP  + 134217728ull;        // 16,777,216
  const size_t OFF_KP   = OFF_QP  + 16777216ull;         // 16,777,216
  const size_t OFF_VB   = OFF_KP  + 16777216ull;         // 134,217,728
  const size_t OFF_VT   = OFF_VB  + 134217728ull;        // 134,217,728
  const size_t OFF_ECA  = OFF_VT  + 134217728ull;        // 33,554,432
  const size_t OFF_AR   = OFF_ECA + 33554432ull;         // 33,554,432
  const size_t OFF_OCT  = OFF_XP;                        // alias: xp dead after k_qkv
  const size_t NEED     = OFF_AR + 33554432ull;          // ~481 MiB
  if (ws_size < NEED) return;                            // cannot run; fail cleanly

  unsigned short* wall = (unsigned short*)(ws + OFF_WALL);
  unsigned short* xp   = (unsigned short*)(ws + OFF_XP);
  unsigned short* qp   = (unsigned short*)(ws + OFF_QP);
  unsigned short* kp   = (unsigned short*)(ws + OFF_KP);
  unsigned short* vb   = (unsigned short*)(ws + OFF_VB);
  unsigned short* vt   = (unsigned short*)(ws + OFF_VT);
  unsigned short* eca  = (unsigned short*)(ws + OFF_ECA);
  unsigned short* ar   = (unsigned short*)(ws + OFF_AR);
  unsigned short* oct  = (unsigned short*)(ws + OFF_OCT);

  k_pack_w      <<<1280, 256, 0, stream>>>(Wq, Wk, Wv, wall);
  k_xp          <<<4096, 256, 0, stream>>>(x, xp);
  k_qkv         <<<5120, 256, 0, stream>>>(xp, wall, bq, bk, bv, qp, kp, vb);
  k_tv          <<<4096, 256, 0, stream>>>(vb, vt);
  k_ecol        <<<1024, 256, 0, stream>>>(qp, kp, eca);
  k_erow_softmax<<<1024, 256, 0, stream>>>(qp, kp, eca, ar);
  k_outrow      <<<4096, 256, 0, stream>>>(vb, ar, x, gamma, out);
  k_outcol      <<<4096, 256, 0, stream>>>(vt, eca, oct);
  k_final       <<<4096, 256, 0, stream>>>(oct, gamma, out);
}

// Round 2
// 1097.205 us; speedup vs baseline: 1.0932x; 1.0932x over previous
//
#include <hip/hip_runtime.h>
#include <hip/hip_bf16.h>

// Criss-Cross Attention, MI355X. Round 2: m97-style k_qkv (global_load_lds,
// XCD swizzle, coalesced LDS-transpose epilogue) + vectorized softmax.
// B=8, C=512, C8=64, S=128. All MFMA = 16x16x32 bf16 (verified layouts):
//   a/b frag: M[row = lane&15][k = (lane>>4)*8 + j], D = A * B^T
//   D frag:   D[row = (lane>>4)*4 + reg][col = lane&15]

#define S 128
#define SS 16384
#define C 512
#define C8 64
#define NEG_BIG -1000000000.0f

using short8 = __attribute__((ext_vector_type(8))) short;
using f32x4  = __attribute__((ext_vector_type(4))) float;

#define GPTR(p) ((const __attribute__((address_space(1))) void*)(p))
#define LPTR(p) ((__attribute__((address_space(3))) void*)(p))

__device__ __forceinline__ unsigned short f2b(float f){
  union { float f; unsigned u; } v; v.f = f;
  unsigned r = (v.u + 0x7fffu + ((v.u >> 16) & 1u)) >> 16;
  return (unsigned short)r;
}
__device__ __forceinline__ float b2f(unsigned short h){
  union { unsigned u; float f; } v; v.u = ((unsigned)h) << 16;
  return v.f;
}

// ---------------- K0a: pack Wq|Wk|Wv -> wall[640][512] bf16 ----------------
__global__ __launch_bounds__(256) void k_pack_w(
    const float* __restrict__ Wq, const float* __restrict__ Wk,
    const float* __restrict__ Wv, unsigned short* __restrict__ wall){
  int i = blockIdx.x * 256 + threadIdx.x;
  if (i >= 640 * C) return;
  int co = i >> 9, ci = i & (C - 1);
  float v;
  if (co < 64)        v = Wq[co * C + ci];
  else if (co < 128)  v = Wk[(co - 64) * C + ci];
  else                v = Wv[(co - 128) * C + ci];
  wall[i] = f2b(v);
}

// ---------------- K0b: x (f32, [b][ci][w][h]) -> xp (bf16, [b][w][h][ci]) ----
__global__ __launch_bounds__(256) void k_xp(
    const float* __restrict__ x, unsigned short* __restrict__ xp){
  __shared__ unsigned short T[128 * 130] __attribute__((aligned(16)));
  int blk = blockIdx.x;                 // ((b*128 + w)*4 + ct)
  int ct = blk & 3; int bw = blk >> 2;
  int w = bw & 127; int b = bw >> 7;
  int tid = threadIdx.x;
  int ci0 = ct * 128;
  const float* xb = x + ((size_t)(b * C + ci0) * S + w) * S;  // + cc*SS + h
  #pragma unroll
  for (int p = 0; p < 16; ++p){
    int idx = p * 256 + tid;            // 0..4095
    int cc = idx >> 5;
    int h4 = (idx & 31) * 4;
    float4 v = *(const float4*)(xb + (size_t)cc * SS + h4);
    unsigned* d = (unsigned*)&T[cc * 130 + h4];
    d[0] = (unsigned)f2b(v.x) | ((unsigned)f2b(v.y) << 16);
    d[1] = (unsigned)f2b(v.z) | ((unsigned)f2b(v.w) << 16);
  }
  __syncthreads();
  unsigned short* xpb = xp + (size_t)(b * S + w) * S * C + ci0;
  #pragma unroll
  for (int p = 0; p < 8; ++p){
    int idx = p * 256 + tid;            // 0..2047
    int h  = idx >> 4;
    int ch = (idx & 15) * 8;            // cc chunk
    unsigned short tmp[8] __attribute__((aligned(16)));
    #pragma unroll
    for (int j = 0; j < 8; ++j) tmp[j] = T[(ch + j) * 130 + h];
    *(uint4*)(xpb + (size_t)h * C + ch) = *(uint4*)tmp;
  }
}

// ---------------- K1: qkv projection GEMM (m97-style) ----------------
// Swizzled grid (5120): pxsub=blk&7, t=blk>>3, cot=t%5, pxg=t/5, px=pxg*8+pxsub
// -> the 5 cot-blocks of one px-tile are temporally adjacent + same XCD.
__global__ __launch_bounds__(256) void k_qkv(
    const unsigned short* __restrict__ xp, const unsigned short* __restrict__ wall,
    const float* __restrict__ bq, const float* __restrict__ bk,
    const float* __restrict__ bv,
    unsigned short* __restrict__ qp, unsigned short* __restrict__ kp,
    unsigned short* __restrict__ vb){
  __shared__ unsigned short sm[17408] __attribute__((aligned(16)));  // 34816 B
  unsigned short* Al = sm;              // [128][64]
  unsigned short* Bl = sm + 8192;       // [128][64]
  unsigned short* Dl = sm;              // alias: [128][136]
  int blk = blockIdx.x;
  int pxsub = blk & 7; int t = blk >> 3;
  int cot = t % 5; int pxg = t / 5;
  int pxt = pxg * 8 + pxsub;            // 0..1023
  int w = pxt & 127, b = pxt >> 7;
  int tid = threadIdx.x, lane = tid & 63, wid = tid >> 6;
  int qd = lane >> 4, ln = lane & 15;
  const unsigned short* asrc0 = wall + (size_t)cot * 128 * C;
  const unsigned short* bsrc0 = xp + (size_t)pxt * 128 * C;
  f32x4 acc[4][4];
  #pragma unroll
  for (int i = 0; i < 4; ++i)
    #pragma unroll
    for (int j = 0; j < 4; ++j) acc[i][j] = (f32x4){0.f, 0.f, 0.f, 0.f};

  for (int kw = 0; kw < 8; ++kw){
    __syncthreads();
    const unsigned short* asrc = asrc0 + kw * 64;
    const unsigned short* bsrc = bsrc0 + kw * 64;
    #pragma unroll
    for (int p = 0; p < 4; ++p){
      int gi = p * 256 + tid;           // 0..1023
      int row = gi >> 3, kc = (gi & 7) * 8;
      __builtin_amdgcn_global_load_lds(GPTR(asrc + (size_t)row * C + kc),
                                       LPTR((char*)Al + gi * 16), 16, 0, 0);
      __builtin_amdgcn_global_load_lds(GPTR(bsrc + (size_t)row * C + kc),
                                       LPTR((char*)Bl + gi * 16), 16, 0, 0);
    }
    __syncthreads();
    #pragma unroll
    for (int ks = 0; ks < 2; ++ks){
      int ko = ks * 32 + qd * 8;
      short8 af[4], bfr[4];
      #pragma unroll
      for (int i = 0; i < 4; ++i)
        af[i] = *(const short8*)&Al[(((wid & 1) * 4 + i) * 16 + ln) * 64 + ko];
      #pragma unroll
      for (int j = 0; j < 4; ++j)
        bfr[j] = *(const short8*)&Bl[(((wid >> 1) * 4 + j) * 16 + ln) * 64 + ko];
      #pragma unroll
      for (int i = 0; i < 4; ++i)
        #pragma unroll
        for (int j = 0; j < 4; ++j)
          acc[i][j] = __builtin_amdgcn_mfma_f32_16x16x32_bf16(af[i], bfr[j], acc[i][j], 0, 0, 0);
    }
  }
  __syncthreads();
  // bias + pack into Dl[co][px] (pitch 136), then coalesced global stores
  float bias_[4][4];
  #pragma unroll
  for (int i = 0; i < 4; ++i){
    int co_l0 = ((wid & 1) * 4 + i) * 16 + qd * 4;
    #pragma unroll
    for (int r = 0; r < 4; ++r){
      int co_l = co_l0 + r;
      bias_[i][r] = (cot == 0) ? (co_l < 64 ? bq[co_l] : bk[co_l - 64])
                               : bv[(cot - 1) * 128 + co_l];
    }
  }
  #pragma unroll
  for (int i = 0; i < 4; ++i){
    int co_l0 = ((wid & 1) * 4 + i) * 16 + qd * 4;
    #pragma unroll
    for (int j = 0; j < 4; ++j){
      int pxl = ((wid >> 1) * 4 + j) * 16 + ln;
      #pragma unroll
      for (int r = 0; r < 4; ++r)
        Dl[(co_l0 + r) * 136 + pxl] = f2b(acc[i][j][r] + bias_[i][r]);
    }
  }
  __syncthreads();
  if (cot == 0){
    unsigned short* qb = qp + (size_t)(b * S + w) * S * C8;
    unsigned short* kb = kp + (size_t)(b * S + w) * S * C8;
    #pragma unroll
    for (int p = 0; p < 4; ++p){
      int idx = p * 256 + tid;          // 0..1023
      int cch = idx & 7, hh = idx >> 3;
      unsigned short tq[8] __attribute__((aligned(16)));
      unsigned short tk[8] __attribute__((aligned(16)));
      #pragma unroll
      for (int jj = 0; jj < 8; ++jj){
        tq[jj] = Dl[(cch * 8 + jj) * 136 + hh];
        tk[jj] = Dl[(64 + cch * 8 + jj) * 136 + hh];
      }
      *(uint4*)(qb + (size_t)hh * C8 + cch * 8) = *(uint4*)tq;
      *(uint4*)(kb + (size_t)hh * C8 + cch * 8) = *(uint4*)tk;
    }
  } else {
    unsigned short* vbb = vb + ((size_t)(b * C + (cot - 1) * 128) * S + w) * S;
    #pragma unroll
    for (int p = 0; p < 8; ++p){
      int idx = p * 256 + tid;          // 0..2047
      int c_l = idx >> 4, hc = (idx & 15) * 8;
      uint4 v = *(const uint4*)&Dl[c_l * 136 + hc];
      *(uint4*)(vbb + (size_t)c_l * SS + hc) = v;
    }
  }
}

// ---------------- K2: vb [b][c][w][h] -> vt [b][c][h][w] ----------------
__global__ __launch_bounds__(256) void k_tv(
    const unsigned short* __restrict__ vb, unsigned short* __restrict__ vt){
  __shared__ unsigned short T[128 * 130] __attribute__((aligned(16)));
  int bc = blockIdx.x;                  // b*C + c
  const unsigned short* src = vb + (size_t)bc * SS;
  unsigned short* dst = vt + (size_t)bc * SS;
  int tid = threadIdx.x;
  #pragma unroll
  for (int p = 0; p < 8; ++p){
    int idx = p * 256 + tid;            // 0..2047
    int wv = idx >> 4, ch = (idx & 15) * 8;
    uint4 v = *(const uint4*)(src + wv * S + ch);
    unsigned* d = (unsigned*)&T[wv * 130 + ch];
    d[0] = v.x; d[1] = v.y; d[2] = v.z; d[3] = v.w;
  }
  __syncthreads();
  #pragma unroll
  for (int p = 0; p < 8; ++p){
    int idx = p * 256 + tid;
    int h = idx >> 4, ch = (idx & 15) * 8;
    unsigned short tmp[8] __attribute__((aligned(16)));
    #pragma unroll
    for (int j = 0; j < 8; ++j) tmp[j] = T[(ch + j) * 130 + h];
    *(uint4*)(dst + h * S + ch) = *(uint4*)tmp;
  }
}

// ---------------- K3: column scores e_col[b][w][h][u] (masked diag), bf16 ---
__global__ __launch_bounds__(256) void k_ecol(
    const unsigned short* __restrict__ qp, const unsigned short* __restrict__ kp,
    unsigned short* __restrict__ eca){
  __shared__ unsigned short Aq[128 * 72] __attribute__((aligned(16)));
  __shared__ unsigned short Bk[128 * 72] __attribute__((aligned(16)));
  int blk = blockIdx.x; int h = blk & 127, b = blk >> 7;
  int tid = threadIdx.x, lane = tid & 63, wid = tid >> 6;
  int qd = lane >> 4, ln = lane & 15;
  #pragma unroll
  for (int p = 0; p < 4; ++p){
    int idx = p * 256 + tid;
    int row = idx >> 3, ch = (idx & 7) * 8;
    *(uint4*)&Aq[row * 72 + ch] = *(const uint4*)(qp + ((size_t)(b * S + row) * S + h) * C8 + ch);
    *(uint4*)&Bk[row * 72 + ch] = *(const uint4*)(kp + ((size_t)(b * S + row) * S + h) * C8 + ch);
  }
  __syncthreads();
  f32x4 acc[4][4];
  #pragma unroll
  for (int i = 0; i < 4; ++i)
    #pragma unroll
    for (int j = 0; j < 4; ++j) acc[i][j] = (f32x4){0.f, 0.f, 0.f, 0.f};
  #pragma unroll
  for (int ks = 0; ks < 2; ++ks){
    int ko = ks * 32 + qd * 8;
    short8 af[4], bfr[4];
    #pragma unroll
    for (int i = 0; i < 4; ++i)
      af[i] = *(const short8*)&Aq[(((wid & 1) * 4 + i) * 16 + ln) * 72 + ko];
    #pragma unroll
    for (int j = 0; j < 4; ++j)
      bfr[j] = *(const short8*)&Bk[(((wid >> 1) * 4 + j) * 16 + ln) * 72 + ko];
    #pragma unroll
    for (int i = 0; i < 4; ++i)
      #pragma unroll
      for (int j = 0; j < 4; ++j)
        acc[i][j] = __builtin_amdgcn_mfma_f32_16x16x32_bf16(af[i], bfr[j], acc[i][j], 0, 0, 0);
  }
  #pragma unroll
  for (int i = 0; i < 4; ++i){
    int w0 = ((wid & 1) * 4 + i) * 16 + qd * 4;
    #pragma unroll
    for (int j = 0; j < 4; ++j){
      int ug = ((wid >> 1) * 4 + j) * 16 + ln;
      #pragma unroll
      for (int r = 0; r < 4; ++r){
        int wg = w0 + r;
        float val = acc[i][j][r];
        if (wg == ug) val = NEG_BIG;
        eca[((size_t)(b * S + wg) * S + h) * S + ug] = f2b(val);
      }
    }
  }
}

// ------- K4: row scores + joint softmax; ac overwrites eca in place; ar out --
__global__ __launch_bounds__(256) void k_erow_softmax(
    const unsigned short* __restrict__ qp, const unsigned short* __restrict__ kp,
    unsigned short* __restrict__ eca, unsigned short* __restrict__ ar){
  __shared__ char sm[36864] __attribute__((aligned(16)));
  unsigned short* Aq = (unsigned short*)sm;              // [128][72]
  unsigned short* Bk = (unsigned short*)(sm + 18432);    // [128][72]
  unsigned short* El = (unsigned short*)sm;              // alias: [128][136] bf16
  float* redm = (float*)(sm + 34816);                    // [256]
  float* reds = (float*)(sm + 35840);                    // [256]
  int blk = blockIdx.x; int w = blk & 127, b = blk >> 7;
  int tid = threadIdx.x, lane = tid & 63, wid = tid >> 6;
  int qd = lane >> 4, ln = lane & 15;
  size_t tb = (size_t)(b * S + w) * SS;                  // tile base (elems)
  {
    const unsigned short* qsrc = qp + (size_t)(b * S + w) * S * C8;
    const unsigned short* ksrc = kp + (size_t)(b * S + w) * S * C8;
    #pragma unroll
    for (int p = 0; p < 4; ++p){
      int idx = p * 256 + tid;
      int row = idx >> 3, ch = (idx & 7) * 8;
      *(uint4*)&Aq[row * 72 + ch] = *(const uint4*)(qsrc + row * C8 + ch);
      *(uint4*)&Bk[row * 72 + ch] = *(const uint4*)(ksrc + row * C8 + ch);
    }
  }
  __syncthreads();
  f32x4 acc[4][4];
  #pragma unroll
  for (int i = 0; i < 4; ++i)
    #pragma unroll
    for (int j = 0; j < 4; ++j) acc[i][j] = (f32x4){0.f, 0.f, 0.f, 0.f};
  #pragma unroll
  for (int ks = 0; ks < 2; ++ks){
    int ko = ks * 32 + qd * 8;
    short8 af[4], bfr[4];
    #pragma unroll
    for (int i = 0; i < 4; ++i)
      af[i] = *(const short8*)&Aq[(((wid & 1) * 4 + i) * 16 + ln) * 72 + ko];
    #pragma unroll
    for (int j = 0; j < 4; ++j)
      bfr[j] = *(const short8*)&Bk[(((wid >> 1) * 4 + j) * 16 + ln) * 72 + ko];
    #pragma unroll
    for (int i = 0; i < 4; ++i)
      #pragma unroll
      for (int j = 0; j < 4; ++j)
        acc[i][j] = __builtin_amdgcn_mfma_f32_16x16x32_bf16(af[i], bfr[j], acc[i][j], 0, 0, 0);
  }
  __syncthreads();     // done with Aq/Bk; El may now alias them
  #pragma unroll
  for (int i = 0; i < 4; ++i){
    int h0 = ((wid & 1) * 4 + i) * 16 + qd * 4;
    #pragma unroll
    for (int j = 0; j < 4; ++j){
      int ul = ((wid >> 1) * 4 + j) * 16 + ln;
      #pragma unroll
      for (int r = 0; r < 4; ++r)
        El[(h0 + r) * 136 + ul] = f2b(acc[i][j][r]);
    }
  }
  __syncthreads();
  // softmax over 256 = [col(128 from eca) | row(128 from El)] per h
  int h = tid >> 1, half = tid & 1;
  const uint4* src4 = (half == 0) ? (const uint4*)(eca + tb + (size_t)h * S)
                                  : (const uint4*)&El[h * 136];
  float mx = -3.0e38f;
  #pragma unroll 4
  for (int u = 0; u < 16; ++u){
    uint4 v = src4[u];
    const unsigned short* e = (const unsigned short*)&v;
    #pragma unroll
    for (int jj = 0; jj < 8; ++jj) mx = fmaxf(mx, b2f(e[jj]));
  }
  redm[tid] = mx;
  __syncthreads();
  float m = fmaxf(mx, redm[tid ^ 1]);
  float s = 0.f;
  #pragma unroll 4
  for (int u = 0; u < 16; ++u){
    uint4 v = src4[u];
    const unsigned short* e = (const unsigned short*)&v;
    #pragma unroll
    for (int jj = 0; jj < 8; ++jj) s += __expf(b2f(e[jj]) - m);
  }
  reds[tid] = s;
  __syncthreads();
  float inv = 1.0f / (s + reds[tid ^ 1]);
  uint4* dst4 = (half == 0) ? (uint4*)(eca + tb + (size_t)h * S)
                            : (uint4*)(ar + tb + (size_t)h * S);
  #pragma unroll 4
  for (int u = 0; u < 16; ++u){
    uint4 v = src4[u];
    const unsigned short* e = (const unsigned short*)&v;
    unsigned short o[8] __attribute__((aligned(16)));
    #pragma unroll
    for (int jj = 0; jj < 8; ++jj) o[jj] = f2b(__expf(b2f(e[jj]) - m) * inv);
    dst4[u] = *(uint4*)o;
  }
}

// ------- K5: out_row: out = gamma * (A_row @ v_row) + x  (writes all of out) --
__global__ __launch_bounds__(256) void k_outrow(
    const unsigned short* __restrict__ vb, const unsigned short* __restrict__ ar,
    const float* __restrict__ x, const float* __restrict__ gamma,
    float* __restrict__ out){
  __shared__ unsigned short Av[128 * 72] __attribute__((aligned(16)));
  __shared__ unsigned short Ba[128 * 72] __attribute__((aligned(16)));
  int blk = blockIdx.x;                 // ((b*128+w)*4 + ct)
  int ct = blk & 3; int bw = blk >> 2;
  int w = bw & 127, b = bw >> 7;
  int tid = threadIdx.x, lane = tid & 63, wid = tid >> 6;
  int qd = lane >> 4, ln = lane & 15;
  size_t tb = (size_t)(b * S + w) * SS;
  f32x4 acc[4][4];
  #pragma unroll
  for (int i = 0; i < 4; ++i)
    #pragma unroll
    for (int j = 0; j < 4; ++j) acc[i][j] = (f32x4){0.f, 0.f, 0.f, 0.f};
  for (int kw = 0; kw < 2; ++kw){
    __syncthreads();
    #pragma unroll
    for (int p = 0; p < 4; ++p){
      int idx = p * 256 + tid;
      int row = idx >> 3, ch = (idx & 7) * 8;
      *(uint4*)&Av[row * 72 + ch] =
        *(const uint4*)(vb + ((size_t)(b * C + ct * 128 + row) * S + w) * S + kw * 64 + ch);
      *(uint4*)&Ba[row * 72 + ch] =
        *(const uint4*)(ar + tb + (size_t)row * S + kw * 64 + ch);
    }
    __syncthreads();
    #pragma unroll
    for (int ks = 0; ks < 2; ++ks){
      int ko = ks * 32 + qd * 8;
      short8 af[4], bfr[4];
      #pragma unroll
      for (int i = 0; i < 4; ++i)
        af[i] = *(const short8*)&Av[(((wid & 1) * 4 + i) * 16 + ln) * 72 + ko];
      #pragma unroll
      for (int j = 0; j < 4; ++j)
        bfr[j] = *(const short8*)&Ba[(((wid >> 1) * 4 + j) * 16 + ln) * 72 + ko];
      #pragma unroll
      for (int i = 0; i < 4; ++i)
        #pragma unroll
        for (int j = 0; j < 4; ++j)
          acc[i][j] = __builtin_amdgcn_mfma_f32_16x16x32_bf16(af[i], bfr[j], acc[i][j], 0, 0, 0);
    }
  }
  float g = gamma[0];
  #pragma unroll
  for (int i = 0; i < 4; ++i){
    int c0 = ((wid & 1) * 4 + i) * 16 + qd * 4;
    #pragma unroll
    for (int j = 0; j < 4; ++j){
      int hl = ((wid >> 1) * 4 + j) * 16 + ln;
      #pragma unroll
      for (int r = 0; r < 4; ++r){
        int cg = ct * 128 + c0 + r;
        size_t o = ((size_t)(b * C + cg) * S + w) * S + hl;
        out[o] = g * acc[i][j][r] + x[o];
      }
    }
  }
}

// ------- K6: out_col -> oct[b][h][c][w] bf16 ----------------
__global__ __launch_bounds__(256) void k_outcol(
    const unsigned short* __restrict__ vt, const unsigned short* __restrict__ eca,
    unsigned short* __restrict__ oct){
  __shared__ unsigned short Av[128 * 72] __attribute__((aligned(16)));
  __shared__ unsigned short Ba[128 * 72] __attribute__((aligned(16)));
  int blk = blockIdx.x;                 // ((b*128+h)*4 + ct)
  int ct = blk & 3; int bh = blk >> 2;
  int h = bh & 127, b = bh >> 7;
  int tid = threadIdx.x, lane = tid & 63, wid = tid >> 6;
  int qd = lane >> 4, ln = lane & 15;
  f32x4 acc[4][4];
  #pragma unroll
  for (int i = 0; i < 4; ++i)
    #pragma unroll
    for (int j = 0; j < 4; ++j) acc[i][j] = (f32x4){0.f, 0.f, 0.f, 0.f};
  for (int kw = 0; kw < 2; ++kw){
    __syncthreads();
    #pragma unroll
    for (int p = 0; p < 4; ++p){
      int idx = p * 256 + tid;
      int row = idx >> 3, ch = (idx & 7) * 8;
      *(uint4*)&Av[row * 72 + ch] =
        *(const uint4*)(vt + ((size_t)(b * C + ct * 128 + row) * S + h) * S + kw * 64 + ch);
      *(uint4*)&Ba[row * 72 + ch] =
        *(const uint4*)(eca + ((size_t)(b * S + row) * S + h) * S + kw * 64 + ch);
    }
    __syncthreads();
    #pragma unroll
    for (int ks = 0; ks < 2; ++ks){
      int ko = ks * 32 + qd * 8;
      short8 af[4], bfr[4];
      #pragma unroll
      for (int i = 0; i < 4; ++i)
        af[i] = *(const short8*)&Av[(((wid & 1) * 4 + i) * 16 + ln) * 72 + ko];
      #pragma unroll
      for (int j = 0; j < 4; ++j)
        bfr[j] = *(const short8*)&Ba[(((wid >> 1) * 4 + j) * 16 + ln) * 72 + ko];
      #pragma unroll
      for (int i = 0; i < 4; ++i)
        #pragma unroll
        for (int j = 0; j < 4; ++j)
          acc[i][j] = __builtin_amdgcn_mfma_f32_16x16x32_bf16(af[i], bfr[j], acc[i][j], 0, 0, 0);
    }
  }
  #pragma unroll
  for (int i = 0; i < 4; ++i){
    int c0 = ((wid & 1) * 4 + i) * 16 + qd * 4;
    #pragma unroll
    for (int j = 0; j < 4; ++j){
      int wl = ((wid >> 1) * 4 + j) * 16 + ln;
      #pragma unroll
      for (int r = 0; r < 4; ++r){
        int cg = ct * 128 + c0 + r;
        oct[((size_t)(b * S + h) * C + cg) * S + wl] = f2b(acc[i][j][r]);
      }
    }
  }
}

// ------- K7: out += gamma * transpose(oct) ----------------
__global__ __launch_bounds__(256) void k_final(
    const unsigned short* __restrict__ oct, const float* __restrict__ gamma,
    float* __restrict__ out){
  __shared__ unsigned short T[128 * 130] __attribute__((aligned(16)));
  int blk = blockIdx.x;                 // b*C + c
  int c = blk & 511, b = blk >> 9;
  int tid = threadIdx.x;
  float g = gamma[0];
  #pragma unroll
  for (int p = 0; p < 8; ++p){
    int idx = p * 256 + tid;
    int hh = idx >> 4, ch = (idx & 15) * 8;
    uint4 v = *(const uint4*)(oct + ((size_t)(b * S + hh) * C + c) * S + ch);
    unsigned* d = (unsigned*)&T[hh * 130 + ch];
    d[0] = v.x; d[1] = v.y; d[2] = v.z; d[3] = v.w;
  }
  __syncthreads();
  #pragma unroll
  for (int p = 0; p < 8; ++p){
    int idx = p * 256 + tid;
    int wv = idx >> 4, hch = (idx & 15) * 8;
    size_t o = ((size_t)(b * C + c) * S + wv) * S + hch;
    float4 o0 = *(float4*)(out + o);
    float4 o1 = *(float4*)(out + o + 4);
    o0.x += g * b2f(T[(hch + 0) * 130 + wv]);
    o0.y += g * b2f(T[(hch + 1) * 130 + wv]);
    o0.z += g * b2f(T[(hch + 2) * 130 + wv]);
    o0.w += g * b2f(T[(hch + 3) * 130 + wv]);
    o1.x += g * b2f(T[(hch + 4) * 130 + wv]);
    o1.y += g * b2f(T[(hch + 5) * 130 + wv]);
    o1.z += g * b2f(T[(hch + 6) * 130 + wv]);
    o1.w += g * b2f(T[(hch + 7) * 130 + wv]);
    *(float4*)(out + o) = o0;
    *(float4*)(out + o + 4) = o1;
  }
}

extern "C" void kernel_launch(void* const* d_in, const int* in_sizes, int n_in,
                              void* d_out, int out_size, void* d_ws, size_t ws_size,
                              hipStream_t stream){
  const float* x     = (const float*)d_in[0];
  const float* Wq    = (const float*)d_in[1];
  const float* bq    = (const float*)d_in[2];
  const float* Wk    = (const float*)d_in[3];
  const float* bk    = (const float*)d_in[4];
  const float* Wv    = (const float*)d_in[5];
  const float* bv    = (const float*)d_in[6];
  const float* gamma = (const float*)d_in[7];
  float* out = (float*)d_out;
  char* ws = (char*)d_ws;

  const size_t OFF_WALL = 0;
  const size_t OFF_XP   = 1ull << 20;                    // 134,217,728
  const size_t OFF_QP   = OFF_XP  + 134217728ull;        // 16,777,216
  const size_t OFF_KP   = OFF_QP  + 16777216ull;         // 16,777,216
  const size_t OFF_VB   = OFF_KP  + 16777216ull;         // 134,217,728
  const size_t OFF_VT   = OFF_VB  + 134217728ull;        // 134,217,728
  const size_t OFF_ECA  = OFF_VT  + 134217728ull;        // 33,554,432
  const size_t OFF_AR   = OFF_ECA + 33554432ull;         // 33,554,432
  const size_t OFF_OCT  = OFF_XP;                        // alias: xp dead after k_qkv
  const size_t NEED     = OFF_AR + 33554432ull;          // ~481 MiB
  if (ws_size < NEED) return;                            // cannot run; fail cleanly

  unsigned short* wall = (unsigned short*)(ws + OFF_WALL);
  unsigned short* xp   = (unsigned short*)(ws + OFF_XP);
  unsigned short* qp   = (unsigned short*)(ws + OFF_QP);
  unsigned short* kp   = (unsigned short*)(ws + OFF_KP);
  unsigned short* vb   = (unsigned short*)(ws + OFF_VB);
  unsigned short* vt   = (unsigned short*)(ws + OFF_VT);
  unsigned short* eca  = (unsigned short*)(ws + OFF_ECA);
  unsigned short* ar   = (unsigned short*)(ws + OFF_AR);
  unsigned short* oct  = (unsigned short*)(ws + OFF_OCT);

  k_pack_w      <<<1280, 256, 0, stream>>>(Wq, Wk, Wv, wall);
  k_xp          <<<4096, 256, 0, stream>>>(x, xp);
  k_qkv         <<<5120, 256, 0, stream>>>(xp, wall, bq, bk, bv, qp, kp, vb);
  k_tv          <<<4096, 256, 0, stream>>>(vb, vt);
  k_ecol        <<<1024, 256, 0, stream>>>(qp, kp, eca);
  k_erow_softmax<<<1024, 256, 0, stream>>>(qp, kp, eca, ar);
  k_outrow      <<<4096, 256, 0, stream>>>(vb, ar, x, gamma, out);
  k_outcol      <<<4096, 256, 0, stream>>>(vt, eca, oct);
  k_final       <<<4096, 256, 0, stream>>>(oct, gamma, out);
}